// Round 1
// baseline (331.294 us; speedup 1.0000x reference)
//
#include <hip/hip_runtime.h>

#define BATCH 8
#define SEQ   1024
#define DIM   768
#define NH    12
#define HD    64
#define NTOK  (BATCH * SEQ)   /* 8192 */
#define QKVN  (3 * DIM)       /* 2304 */

typedef short bf8   __attribute__((ext_vector_type(8)));  // 8 bf16 (bit pattern in shorts)
typedef short bf4   __attribute__((ext_vector_type(4)));
typedef float f32x4 __attribute__((ext_vector_type(4)));

// fp32 -> bf16 (RNE), raw bits in short
static __device__ __forceinline__ short f2bf(float f) {
    unsigned u = __float_as_uint(f);
    u += 0x7fffu + ((u >> 16) & 1u);
    return (short)(u >> 16);
}

// ---------------------------------------------------------------------------
// Prep: w[R][C] fp32 -> out[C][R] bf16 (W^T layout, contiguous-k rows for B frags)
__global__ __launch_bounds__(256) void transpose_bf16_k(
        const float* __restrict__ in, short* __restrict__ out, int R, int C) {
    int idx = blockIdx.x * 256 + threadIdx.x;
    if (idx >= R * C) return;
    int c = idx / R;
    int r = idx - c * R;
    out[idx] = f2bf(in[(size_t)r * C + c]);   // out[c*R + r] == out[idx]; writes coalesced
}

// ---------------------------------------------------------------------------
// GEMM1: qkv = x @ w_qkv.  x fp32 [8192][768] (converted inline), WT bf16 [2304][768].
// 64x64 tile / block, 4 waves in 2x2, MFMA 16x16x32 bf16, K-step 32.
// Epilogue scatters each 64-col tile (== one (three,head)) into Q/K/V [B,H,N,D] bf16.
__global__ __launch_bounds__(256) void gemm_qkv_k(
        const float* __restrict__ X, const short* __restrict__ WT,
        short* __restrict__ Qb, short* __restrict__ Kb, short* __restrict__ Vb) {
    __shared__ short a_lds[64][40];   // +8 pad: 80B rows, 16B aligned, 2-way banks (free)
    __shared__ short b_lds[64][40];
    const int tid  = threadIdx.x;
    const int lane = tid & 63;
    const int wid  = tid >> 6;
    const int ln   = lane & 15;
    const int quad = lane >> 4;
    const int m0 = blockIdx.y * 64;
    const int n0 = blockIdx.x * 64;
    const int wm = (wid >> 1) * 32;
    const int wn = (wid & 1) * 32;

    const int srow = tid >> 2;         // 0..63
    const int sks  = (tid & 3) * 8;    // 0,8,16,24
    const float* xrow = X  + (size_t)(m0 + srow) * DIM;
    const short* wrow = WT + (size_t)(n0 + srow) * DIM;

    const f32x4 vzero = {0.f, 0.f, 0.f, 0.f};
    f32x4 acc[2][2];
    acc[0][0] = vzero; acc[0][1] = vzero; acc[1][0] = vzero; acc[1][1] = vzero;

    for (int kt = 0; kt < DIM; kt += 32) {
        __syncthreads();
        f32x4 x0 = *(const f32x4*)(xrow + kt + sks);
        f32x4 x1 = *(const f32x4*)(xrow + kt + sks + 4);
        bf8 av;
        av[0] = f2bf(x0[0]); av[1] = f2bf(x0[1]); av[2] = f2bf(x0[2]); av[3] = f2bf(x0[3]);
        av[4] = f2bf(x1[0]); av[5] = f2bf(x1[1]); av[6] = f2bf(x1[2]); av[7] = f2bf(x1[3]);
        *(bf8*)&a_lds[srow][sks] = av;
        *(bf8*)&b_lds[srow][sks] = *(const bf8*)(wrow + kt + sks);
        __syncthreads();
        bf8 af[2], bw[2];
        af[0] = *(const bf8*)&a_lds[wm + ln][quad * 8];       // A[m=ln][k=quad*8+j]
        af[1] = *(const bf8*)&a_lds[wm + 16 + ln][quad * 8];
        bw[0] = *(const bf8*)&b_lds[wn + ln][quad * 8];       // B^T[n=ln][k=quad*8+j]
        bw[1] = *(const bf8*)&b_lds[wn + 16 + ln][quad * 8];
        #pragma unroll
        for (int mi = 0; mi < 2; mi++)
            #pragma unroll
            for (int ni = 0; ni < 2; ni++)
                acc[mi][ni] = __builtin_amdgcn_mfma_f32_16x16x32_bf16(
                        af[mi], bw[ni], acc[mi][ni], 0, 0, 0);
    }

    // n0 is a multiple of 64 -> tile cols are exactly one (three, head) pair
    const int three = n0 / DIM;
    const int h = (n0 - three * DIM) / HD;
    short* dst = (three == 0) ? Qb : ((three == 1) ? Kb : Vb);
    const int b = m0 / SEQ;
    const size_t bh_base = (size_t)(b * NH + h) * SEQ * HD;
    #pragma unroll
    for (int mi = 0; mi < 2; mi++) {
        #pragma unroll
        for (int ni = 0; ni < 2; ni++) {
            const int d = wn + ni * 16 + ln;                  // C/D col = lane&15
            #pragma unroll
            for (int r = 0; r < 4; r++) {                    // C/D row = quad*4+r
                int m = m0 + wm + mi * 16 + quad * 4 + r;
                int tok = m - b * SEQ;
                dst[bh_base + (size_t)tok * HD + d] = f2bf(acc[mi][ni][r]);
            }
        }
    }
}

// ---------------------------------------------------------------------------
// Flash attention: block = (b,h) x 64-query tile, 4 waves x 16 queries.
// 32-key tiles: S = Q K^T (2 MFMA n-subtiles x 2 k-chunks), online softmax in C-layout,
// P -> LDS -> A-operand layout, O += P V with V natural-layout LDS (scalar b-frag reads).
__global__ __launch_bounds__(256) void attn_k(
        const short* __restrict__ Qb, const short* __restrict__ Kb,
        const short* __restrict__ Vb, short* __restrict__ Ob) {
    __shared__ short k_lds[32][72];       // 144B rows: b128-aligned, 2-way banks
    __shared__ short v_lds[32][68];       // 136B rows: scalar reads, 2-way banks (free)
    __shared__ short p_lds[4][16][40];    // per-wave P tile, 80B rows b128-aligned
    const int tid  = threadIdx.x;
    const int lane = tid & 63;
    const int wid  = tid >> 6;
    const int ln   = lane & 15;
    const int quad = lane >> 4;
    const int bh = blockIdx.y;            // b*12 + h
    const int qt = blockIdx.x;            // 0..15
    const size_t base = (size_t)bh * SEQ * HD;
    const short* qg = Qb + base;
    const short* kg = Kb + base;
    const short* vg = Vb + base;
    const int q0 = qt * 64 + wid * 16;

    // Q fragments held in registers for the whole block
    bf8 aq[2];
    aq[0] = *(const bf8*)(qg + (size_t)(q0 + ln) * HD + quad * 8);
    aq[1] = *(const bf8*)(qg + (size_t)(q0 + ln) * HD + 32 + quad * 8);

    const f32x4 vzero = {0.f, 0.f, 0.f, 0.f};
    f32x4 o_acc[4];
    o_acc[0] = vzero; o_acc[1] = vzero; o_acc[2] = vzero; o_acc[3] = vzero;
    float m_i[4] = {-1e30f, -1e30f, -1e30f, -1e30f};
    float l_i[4] = {0.f, 0.f, 0.f, 0.f};

    const int srow = tid >> 3;            // 0..31 (token in tile)
    const int sd   = (tid & 7) * 8;       // d offset

    for (int kt = 0; kt < SEQ / 32; kt++) {
        __syncthreads();
        *(bf8*)&k_lds[srow][sd] = *(const bf8*)(kg + (size_t)(kt * 32 + srow) * HD + sd);
        // v_lds rows are 136B (8B-aligned only) -> two b64 writes
        *(bf4*)&v_lds[srow][sd]     = *(const bf4*)(vg + (size_t)(kt * 32 + srow) * HD + sd);
        *(bf4*)&v_lds[srow][sd + 4] = *(const bf4*)(vg + (size_t)(kt * 32 + srow) * HD + sd + 4);
        __syncthreads();

        // S[q][key]: A=Q, B-frag = K[key=ln+ni*16][d=quad*8+j] (contraction over d=64)
        f32x4 s[2];
        #pragma unroll
        for (int ni = 0; ni < 2; ni++) {
            bf8 b0 = *(const bf8*)&k_lds[ni * 16 + ln][quad * 8];
            bf8 b1 = *(const bf8*)&k_lds[ni * 16 + ln][32 + quad * 8];
            s[ni] = __builtin_amdgcn_mfma_f32_16x16x32_bf16(aq[0], b0, vzero, 0, 0, 0);
            s[ni] = __builtin_amdgcn_mfma_f32_16x16x32_bf16(aq[1], b1, s[ni], 0, 0, 0);
        }

        // online softmax: rows live at quad*4+r, cols span lanes (quad-groups of 16)
        float p0[4], p1[4], alpha[4];
        #pragma unroll
        for (int r = 0; r < 4; r++) {
            float s0 = s[0][r] * 0.125f;
            float s1 = s[1][r] * 0.125f;
            float tm = fmaxf(s0, s1);
            tm = fmaxf(tm, __shfl_xor(tm, 1, 64));
            tm = fmaxf(tm, __shfl_xor(tm, 2, 64));
            tm = fmaxf(tm, __shfl_xor(tm, 4, 64));
            tm = fmaxf(tm, __shfl_xor(tm, 8, 64));
            float nm = fmaxf(m_i[r], tm);
            alpha[r] = __expf(m_i[r] - nm);
            m_i[r] = nm;
            p0[r] = __expf(s0 - nm);
            p1[r] = __expf(s1 - nm);
            float rs = p0[r] + p1[r];
            rs += __shfl_xor(rs, 1, 64);
            rs += __shfl_xor(rs, 2, 64);
            rs += __shfl_xor(rs, 4, 64);
            rs += __shfl_xor(rs, 8, 64);
            l_i[r] = l_i[r] * alpha[r] + rs;
        }

        // P: C-layout -> LDS (per-wave region) -> read back in A-operand layout
        #pragma unroll
        for (int r = 0; r < 4; r++) {
            p_lds[wid][quad * 4 + r][ln]      = f2bf(p0[r]);
            p_lds[wid][quad * 4 + r][16 + ln] = f2bf(p1[r]);
        }
        #pragma unroll
        for (int c = 0; c < 4; c++) {
            #pragma unroll
            for (int r = 0; r < 4; r++) o_acc[c][r] *= alpha[r];
        }
        bf8 ap_ = *(const bf8*)&p_lds[wid][ln][quad * 8];   // A[m=q=ln][k=key=quad*8+j]
        #pragma unroll
        for (int c = 0; c < 4; c++) {
            bf8 bv;
            #pragma unroll
            for (int j = 0; j < 8; j++)                     // B[k=key][n=d=c*16+ln]
                bv[j] = v_lds[quad * 8 + j][c * 16 + ln];
            o_acc[c] = __builtin_amdgcn_mfma_f32_16x16x32_bf16(ap_, bv, o_acc[c], 0, 0, 0);
        }
    }

    // epilogue: O /= l, store bf16 to attn buffer [b][tok][h*64 + d]
    const int b = bh / NH;
    const int h = bh - b * NH;
    #pragma unroll
    for (int r = 0; r < 4; r++) {
        float inv = 1.0f / l_i[r];
        int tok = q0 + quad * 4 + r;
        size_t off = (size_t)(b * SEQ + tok) * DIM + h * HD;
        #pragma unroll
        for (int c = 0; c < 4; c++)
            Ob[off + c * 16 + ln] = f2bf(o_acc[c][r] * inv);
    }
}

// ---------------------------------------------------------------------------
// GEMM2: out = attn @ w_proj + b_proj.  A bf16 [8192][768], WT bf16 [768][768], out fp32.
__global__ __launch_bounds__(256) void gemm_proj_k(
        const short* __restrict__ A, const short* __restrict__ WT,
        const float* __restrict__ bias, float* __restrict__ Out) {
    __shared__ short a_lds[64][40];
    __shared__ short b_lds[64][40];
    const int tid  = threadIdx.x;
    const int lane = tid & 63;
    const int wid  = tid >> 6;
    const int ln   = lane & 15;
    const int quad = lane >> 4;
    const int m0 = blockIdx.y * 64;
    const int n0 = blockIdx.x * 64;
    const int wm = (wid >> 1) * 32;
    const int wn = (wid & 1) * 32;

    const int srow = tid >> 2;
    const int sks  = (tid & 3) * 8;
    const short* arow = A  + (size_t)(m0 + srow) * DIM;
    const short* wrow = WT + (size_t)(n0 + srow) * DIM;

    const f32x4 vzero = {0.f, 0.f, 0.f, 0.f};
    f32x4 acc[2][2];
    acc[0][0] = vzero; acc[0][1] = vzero; acc[1][0] = vzero; acc[1][1] = vzero;

    for (int kt = 0; kt < DIM; kt += 32) {
        __syncthreads();
        *(bf8*)&a_lds[srow][sks] = *(const bf8*)(arow + kt + sks);
        *(bf8*)&b_lds[srow][sks] = *(const bf8*)(wrow + kt + sks);
        __syncthreads();
        bf8 af[2], bw[2];
        af[0] = *(const bf8*)&a_lds[wm + ln][quad * 8];
        af[1] = *(const bf8*)&a_lds[wm + 16 + ln][quad * 8];
        bw[0] = *(const bf8*)&b_lds[wn + ln][quad * 8];
        bw[1] = *(const bf8*)&b_lds[wn + 16 + ln][quad * 8];
        #pragma unroll
        for (int mi = 0; mi < 2; mi++)
            #pragma unroll
            for (int ni = 0; ni < 2; ni++)
                acc[mi][ni] = __builtin_amdgcn_mfma_f32_16x16x32_bf16(
                        af[mi], bw[ni], acc[mi][ni], 0, 0, 0);
    }

    #pragma unroll
    for (int ni = 0; ni < 2; ni++) {
        int n = n0 + wn + ni * 16 + ln;
        float bi = bias[n];
        #pragma unroll
        for (int mi = 0; mi < 2; mi++) {
            #pragma unroll
            for (int r = 0; r < 4; r++) {
                int m = m0 + wm + mi * 16 + quad * 4 + r;
                Out[(size_t)m * DIM + n] = acc[mi][ni][r] + bi;
            }
        }
    }
}

// ---------------------------------------------------------------------------
extern "C" void kernel_launch(void* const* d_in, const int* in_sizes, int n_in,
                              void* d_out, int out_size, void* d_ws, size_t ws_size,
                              hipStream_t stream) {
    const float* x      = (const float*)d_in[0];
    const float* w_qkv  = (const float*)d_in[1];
    const float* w_proj = (const float*)d_in[2];
    const float* b_proj = (const float*)d_in[3];
    float* out = (float*)d_out;
    char* ws = (char*)d_ws;

    // ws layout (bytes): total 55,050,240
    short* wqkvT  = (short*)(ws);              //  3,538,944 B  [2304][768]
    short* wprojT = (short*)(ws +  3538944);   //  1,179,648 B  [768][768]
    short* qb     = (short*)(ws +  4718592);   // 12,582,912 B  [B,H,N,D]
    short* kb     = (short*)(ws + 17301504);   // 12,582,912 B
    short* vb     = (short*)(ws + 29884416);   // 12,582,912 B
    short* attn   = (short*)(ws + 42467328);   // 12,582,912 B  [B,N,768]

    transpose_bf16_k<<<dim3((DIM * QKVN + 255) / 256), 256, 0, stream>>>(w_qkv, wqkvT, DIM, QKVN);
    transpose_bf16_k<<<dim3((DIM * DIM + 255) / 256), 256, 0, stream>>>(w_proj, wprojT, DIM, DIM);
    gemm_qkv_k<<<dim3(QKVN / 64, NTOK / 64), 256, 0, stream>>>(x, wqkvT, qb, kb, vb);
    attn_k<<<dim3(SEQ / 64, BATCH * NH), 256, 0, stream>>>(qb, kb, vb, attn);
    gemm_proj_k<<<dim3(DIM / 64, NTOK / 64), 256, 0, stream>>>(attn, wprojT, b_proj, out);
}

// Round 2
// 278.383 us; speedup vs baseline: 1.1901x; 1.1901x over previous
//
#include <hip/hip_runtime.h>

#define BATCH 8
#define SEQ   1024
#define DIM   768
#define NH    12
#define HD    64
#define NTOK  (BATCH * SEQ)   /* 8192 */
#define QKVN  (3 * DIM)       /* 2304 */

typedef short bf8   __attribute__((ext_vector_type(8)));  // 8 bf16 bit patterns
typedef short bf4   __attribute__((ext_vector_type(4)));
typedef float f32x4 __attribute__((ext_vector_type(4)));

static __device__ __forceinline__ short f2bf(float f) {
    unsigned u = __float_as_uint(f);
    u += 0x7fffu + ((u >> 16) & 1u);
    return (short)(u >> 16);
}

// async global->LDS, 16B per lane, dest = wave-uniform base + lane*16
static __device__ __forceinline__ void gload_lds16(const short* g, short* l) {
    __builtin_amdgcn_global_load_lds(
        (const __attribute__((address_space(1))) void*)g,
        (__attribute__((address_space(3))) void*)l, 16, 0, 0);
}

// ---------------------------------------------------------------------------
// x fp32 -> bf16, 4 elements/thread
__global__ __launch_bounds__(256) void convx_k(const float* __restrict__ in,
                                               short* __restrict__ out) {
    int i = blockIdx.x * 256 + threadIdx.x;
    f32x4 v = ((const f32x4*)in)[i];
    bf4 o;
    o[0] = f2bf(v[0]); o[1] = f2bf(v[1]); o[2] = f2bf(v[2]); o[3] = f2bf(v[3]);
    ((bf4*)out)[i] = o;
}

// w[R][C] fp32 -> out[C][R] bf16 (W^T, contiguous-k rows)
__global__ __launch_bounds__(256) void transpose_bf16_k(
        const float* __restrict__ in, short* __restrict__ out, int R, int C) {
    int idx = blockIdx.x * 256 + threadIdx.x;
    if (idx >= R * C) return;
    int c = idx / R;
    int r = idx - c * R;
    out[idx] = f2bf(in[(size_t)r * C + c]);
}

// ---------------------------------------------------------------------------
// m97-style GEMM core: 128x128 tile, 4 waves (2x2 of 64x64), BK=32,
// global_load_lds width=16, XOR chunk swizzle (chunk ^ (row>>1)&3) for
// conflict-free (2-way) ds_read_b128 frag reads from unpadded [128][32] tiles.
// A: [M][768] bf16 row-major.  WT: [N][768] bf16 row-major (= W^T).
static __device__ __forceinline__ void gemm_core_128(
        const short* __restrict__ A, const short* __restrict__ WT,
        int m0, int n0, int tid, short* aL, short* bL, f32x4 acc[4][4]) {
    const int lane = tid & 63;
    const int wid  = tid >> 6;
    const int ln   = lane & 15;
    const int quad = lane >> 4;
    const int wm = (wid >> 1) * 64;
    const int wn = (wid & 1) * 64;
    const int sw = (quad ^ ((ln >> 1) & 3)) * 8;   // swizzled chunk for frag reads

    // per-lane staging source offsets (2 rounds per wave per tile)
    int fc0 = (wid * 2) * 64 + lane;       // flat 16B-chunk index, round 0
    int fc1 = fc0 + 64;                    // round 1
    int r0 = fc0 >> 2, c0 = (fc0 & 3) ^ ((r0 >> 1) & 3);
    int r1 = fc1 >> 2, c1 = (fc1 & 3) ^ ((r1 >> 1) & 3);
    const short* a0 = A + (size_t)(m0 + r0) * DIM + c0 * 8;
    const short* a1 = A + (size_t)(m0 + r1) * DIM + c1 * 8;
    const short* b0 = WT + (size_t)(n0 + r0) * DIM + c0 * 8;
    const short* b1 = WT + (size_t)(n0 + r1) * DIM + c1 * 8;
    short* aD0 = aL + (wid * 2) * 512;     // 1024B per round, wave-uniform
    short* aD1 = aD0 + 512;
    short* bD0 = bL + (wid * 2) * 512;
    short* bD1 = bD0 + 512;

    for (int kt = 0; kt < DIM; kt += 32) {
        __syncthreads();
        gload_lds16(a0 + kt, aD0);
        gload_lds16(a1 + kt, aD1);
        gload_lds16(b0 + kt, bD0);
        gload_lds16(b1 + kt, bD1);
        __syncthreads();   // compiler emits vmcnt(0) drain before barrier
        bf8 af[4], bw[4];
        #pragma unroll
        for (int mi = 0; mi < 4; mi++)
            af[mi] = *(const bf8*)&aL[(wm + mi * 16 + ln) * 32 + sw];
        #pragma unroll
        for (int ni = 0; ni < 4; ni++)
            bw[ni] = *(const bf8*)&bL[(wn + ni * 16 + ln) * 32 + sw];
        #pragma unroll
        for (int mi = 0; mi < 4; mi++)
            #pragma unroll
            for (int ni = 0; ni < 4; ni++)
                acc[mi][ni] = __builtin_amdgcn_mfma_f32_16x16x32_bf16(
                        af[mi], bw[ni], acc[mi][ni], 0, 0, 0);
    }
}

// ---------------------------------------------------------------------------
// GEMM1: qkv = xb @ w_qkv; scatter Q,K -> [B,H,N,D], V -> V^T [B,H,D,N]
__global__ __launch_bounds__(256) void gemm_qkv_k(
        const short* __restrict__ X, const short* __restrict__ WT,
        short* __restrict__ Qb, short* __restrict__ Kb, short* __restrict__ VT) {
    __shared__ short aL[128 * 32];
    __shared__ short bL[128 * 32];
    const int tid  = threadIdx.x;
    const int lane = tid & 63;
    const int wid  = tid >> 6;
    const int ln   = lane & 15;
    const int quad = lane >> 4;
    const int m0 = blockIdx.y * 128;
    const int n0 = blockIdx.x * 128;
    const int wm = (wid >> 1) * 64;
    const int wn = (wid & 1) * 64;

    const f32x4 vzero = {0.f, 0.f, 0.f, 0.f};
    f32x4 acc[4][4];
    #pragma unroll
    for (int i = 0; i < 4; i++)
        #pragma unroll
        for (int j = 0; j < 4; j++) acc[i][j] = vzero;

    gemm_core_128(X, WT, m0, n0, tid, aL, bL, acc);

    const int b = m0 / SEQ;                 // 128-row tile never crosses batch
    const int mt = m0 - b * SEQ;
    #pragma unroll
    for (int ni = 0; ni < 4; ni++) {
        const int nb = n0 + wn + ni * 16;   // frag cols within one 64-col head group
        const int three = nb / DIM;
        const int rem = nb - three * DIM;
        const int h = rem >> 6;
        const int d = (rem & 63) + ln;
        const size_t bh = (size_t)(b * NH + h);
        if (three < 2) {
            short* dst = (three == 0 ? Qb : Kb) + bh * SEQ * HD;
            #pragma unroll
            for (int mi = 0; mi < 4; mi++) {
                #pragma unroll
                for (int r = 0; r < 4; r++) {
                    int tok = mt + wm + mi * 16 + quad * 4 + r;
                    dst[(size_t)tok * HD + d] = f2bf(acc[mi][ni][r]);
                }
            }
        } else {
            short* dst = VT + bh * HD * SEQ + (size_t)d * SEQ;
            #pragma unroll
            for (int mi = 0; mi < 4; mi++) {
                int tok0 = mt + wm + mi * 16 + quad * 4;
                bf4 v;
                v[0] = f2bf(acc[mi][ni][0]); v[1] = f2bf(acc[mi][ni][1]);
                v[2] = f2bf(acc[mi][ni][2]); v[3] = f2bf(acc[mi][ni][3]);
                *(bf4*)&dst[tok0] = v;
            }
        }
    }
}

// ---------------------------------------------------------------------------
// Flash attention v2: block = (b,h) x 128 queries, 4 waves x 32 queries.
// 64-key iterations; K and V^T fragments read DIRECTLY from global (L2-served);
// no barriers in the K-loop. P round-trips through a per-wave padded LDS tile.
__global__ __launch_bounds__(256) void attn_k(
        const short* __restrict__ Qb, const short* __restrict__ Kb,
        const short* __restrict__ VT, short* __restrict__ Ob) {
    __shared__ short p_lds[4][32][72];     // per-wave P, 144B rows: 2-way banks, 16B aligned
    const int tid  = threadIdx.x;
    const int lane = tid & 63;
    const int wid  = tid >> 6;
    const int ln   = lane & 15;
    const int quad = lane >> 4;
    const int bh = blockIdx.y;
    const int qt = blockIdx.x;
    const size_t base = (size_t)bh * SEQ * HD;
    const short* qg = Qb + base;
    const short* kg = Kb + base;
    const short* vg = VT + base;           // V^T: [d][tok]
    const int q0 = qt * 128 + wid * 32;
    short* pw = &p_lds[wid][0][0];

    bf8 aq[2][2];
    #pragma unroll
    for (int mi = 0; mi < 2; mi++)
        #pragma unroll
        for (int kc = 0; kc < 2; kc++)
            aq[mi][kc] = *(const bf8*)&qg[(size_t)(q0 + mi * 16 + ln) * HD + kc * 32 + quad * 8];

    const f32x4 vzero = {0.f, 0.f, 0.f, 0.f};
    f32x4 o[2][4];
    float m_i[2][4], l_i[2][4];
    #pragma unroll
    for (int mi = 0; mi < 2; mi++) {
        #pragma unroll
        for (int c = 0; c < 4; c++) o[mi][c] = vzero;
        #pragma unroll
        for (int r = 0; r < 4; r++) { m_i[mi][r] = -1e30f; l_i[mi][r] = 0.f; }
    }

    for (int kt = 0; kt < SEQ / 64; kt++) {
        // S = Q K^T over 64 keys: B-frag = K natural layout rows
        f32x4 s[2][4];
        #pragma unroll
        for (int ni = 0; ni < 4; ni++) {
            const short* krow = &kg[(size_t)(kt * 64 + ni * 16 + ln) * HD + quad * 8];
            bf8 bk0 = *(const bf8*)krow;
            bf8 bk1 = *(const bf8*)(krow + 32);
            #pragma unroll
            for (int mi = 0; mi < 2; mi++) {
                f32x4 t = __builtin_amdgcn_mfma_f32_16x16x32_bf16(aq[mi][0], bk0, vzero, 0, 0, 0);
                s[mi][ni] = __builtin_amdgcn_mfma_f32_16x16x32_bf16(aq[mi][1], bk1, t, 0, 0, 0);
            }
        }
        // online softmax, rows at quad*4+r, 16-lane (quad) reductions
        #pragma unroll
        for (int mi = 0; mi < 2; mi++) {
            #pragma unroll
            for (int r = 0; r < 4; r++) {
                float v0 = s[mi][0][r] * 0.125f;
                float v1 = s[mi][1][r] * 0.125f;
                float v2 = s[mi][2][r] * 0.125f;
                float v3 = s[mi][3][r] * 0.125f;
                float tm = fmaxf(fmaxf(v0, v1), fmaxf(v2, v3));
                tm = fmaxf(tm, __shfl_xor(tm, 1, 64));
                tm = fmaxf(tm, __shfl_xor(tm, 2, 64));
                tm = fmaxf(tm, __shfl_xor(tm, 4, 64));
                tm = fmaxf(tm, __shfl_xor(tm, 8, 64));
                float nm = fmaxf(m_i[mi][r], tm);
                float al = __expf(m_i[mi][r] - nm);
                m_i[mi][r] = nm;
                float p0 = __expf(v0 - nm), p1 = __expf(v1 - nm);
                float p2 = __expf(v2 - nm), p3 = __expf(v3 - nm);
                float rs = (p0 + p1) + (p2 + p3);
                rs += __shfl_xor(rs, 1, 64);
                rs += __shfl_xor(rs, 2, 64);
                rs += __shfl_xor(rs, 4, 64);
                rs += __shfl_xor(rs, 8, 64);
                l_i[mi][r] = l_i[mi][r] * al + rs;
                int prow = mi * 16 + quad * 4 + r;
                pw[prow * 72 + ln]      = f2bf(p0);
                pw[prow * 72 + 16 + ln] = f2bf(p1);
                pw[prow * 72 + 32 + ln] = f2bf(p2);
                pw[prow * 72 + 48 + ln] = f2bf(p3);
                #pragma unroll
                for (int c = 0; c < 4; c++) o[mi][c][r] *= al;
            }
        }
        // O += P V : A-frag from per-wave LDS, B-frag straight from V^T global
        #pragma unroll
        for (int kc = 0; kc < 2; kc++) {
            bf8 ap[2];
            #pragma unroll
            for (int mi = 0; mi < 2; mi++)
                ap[mi] = *(const bf8*)&pw[(mi * 16 + ln) * 72 + kc * 32 + quad * 8];
            #pragma unroll
            for (int c = 0; c < 4; c++) {
                bf8 bv = *(const bf8*)&vg[(size_t)(c * 16 + ln) * SEQ + kt * 64 + kc * 32 + quad * 8];
                #pragma unroll
                for (int mi = 0; mi < 2; mi++)
                    o[mi][c] = __builtin_amdgcn_mfma_f32_16x16x32_bf16(ap[mi], bv, o[mi][c], 0, 0, 0);
            }
        }
    }

    const int b = bh / NH;
    const int h = bh - b * NH;
    #pragma unroll
    for (int mi = 0; mi < 2; mi++) {
        #pragma unroll
        for (int r = 0; r < 4; r++) {
            float inv = 1.0f / l_i[mi][r];
            int tok = q0 + mi * 16 + quad * 4 + r;
            size_t off = (size_t)(b * SEQ + tok) * DIM + h * HD;
            #pragma unroll
            for (int c = 0; c < 4; c++)
                Ob[off + c * 16 + ln] = f2bf(o[mi][c][r] * inv);
        }
    }
}

// ---------------------------------------------------------------------------
// GEMM2: out = attn @ w_proj + b_proj, fp32 out
__global__ __launch_bounds__(256) void gemm_proj_k(
        const short* __restrict__ A, const short* __restrict__ WT,
        const float* __restrict__ bias, float* __restrict__ Out) {
    __shared__ short aL[128 * 32];
    __shared__ short bL[128 * 32];
    const int tid  = threadIdx.x;
    const int lane = tid & 63;
    const int ln   = lane & 15;
    const int quad = lane >> 4;
    const int wid  = tid >> 6;
    const int m0 = blockIdx.y * 128;
    const int n0 = blockIdx.x * 128;
    const int wm = (wid >> 1) * 64;
    const int wn = (wid & 1) * 64;

    const f32x4 vzero = {0.f, 0.f, 0.f, 0.f};
    f32x4 acc[4][4];
    #pragma unroll
    for (int i = 0; i < 4; i++)
        #pragma unroll
        for (int j = 0; j < 4; j++) acc[i][j] = vzero;

    gemm_core_128(A, WT, m0, n0, tid, aL, bL, acc);

    #pragma unroll
    for (int ni = 0; ni < 4; ni++) {
        int n = n0 + wn + ni * 16 + ln;
        float bi = bias[n];
        #pragma unroll
        for (int mi = 0; mi < 4; mi++) {
            #pragma unroll
            for (int r = 0; r < 4; r++) {
                int m = m0 + wm + mi * 16 + quad * 4 + r;
                Out[(size_t)m * DIM + n] = acc[mi][ni][r] + bi;
            }
        }
    }
}

// ---------------------------------------------------------------------------
extern "C" void kernel_launch(void* const* d_in, const int* in_sizes, int n_in,
                              void* d_out, int out_size, void* d_ws, size_t ws_size,
                              hipStream_t stream) {
    const float* x      = (const float*)d_in[0];
    const float* w_qkv  = (const float*)d_in[1];
    const float* w_proj = (const float*)d_in[2];
    const float* b_proj = (const float*)d_in[3];
    float* out = (float*)d_out;
    char* ws = (char*)d_ws;

    // ws layout (bytes), total 55,050,240 — xb aliases attn (xb dead before attn_k writes)
    short* wqkvT  = (short*)(ws);              //  3,538,944  [2304][768]
    short* wprojT = (short*)(ws +  3538944);   //  1,179,648  [768][768]
    short* qb     = (short*)(ws +  4718592);   // 12,582,912  [B,H,N,D]
    short* kb     = (short*)(ws + 17301504);   // 12,582,912  [B,H,N,D]
    short* vt     = (short*)(ws + 29884416);   // 12,582,912  [B,H,D,N]
    short* xb     = (short*)(ws + 42467328);   // 12,582,912  [B,N,768] (bf16 x, then attn out)
    short* attn   = xb;

    convx_k<<<dim3(NTOK * DIM / 1024), 256, 0, stream>>>(x, xb);
    transpose_bf16_k<<<dim3((DIM * QKVN + 255) / 256), 256, 0, stream>>>(w_qkv, wqkvT, DIM, QKVN);
    transpose_bf16_k<<<dim3((DIM * DIM + 255) / 256), 256, 0, stream>>>(w_proj, wprojT, DIM, DIM);
    gemm_qkv_k<<<dim3(QKVN / 128, NTOK / 128), 256, 0, stream>>>(xb, wqkvT, qb, kb, vt);
    attn_k<<<dim3(SEQ / 128, BATCH * NH), 256, 0, stream>>>(qb, kb, vt, attn);
    gemm_proj_k<<<dim3(DIM / 128, NTOK / 128), 256, 0, stream>>>(attn, wprojT, b_proj, out);
}